// Round 2
// baseline (2874.077 us; speedup 1.0000x reference)
//
#include <hip/hip_runtime.h>
#include <stdint.h>

#define B_  8
#define L_  512
#define E_  256
#define H_  128
#define W_  128
#define NH_ 8
#define HD_ 32

typedef unsigned short ushort_t;

__device__ __forceinline__ float bf2f(ushort_t u) {
    union { unsigned int i; float f; } x;
    x.i = ((unsigned int)u) << 16;
    return x.f;
}
__device__ __forceinline__ ushort_t f2bf(float f) {
    union { float f; unsigned int i; } x;
    x.f = f;
    unsigned int r = x.i + 0x7FFFu + ((x.i >> 16) & 1u);
    return (ushort_t)(r >> 16);
}

// ---------------- mean reductions (fused before projection; mean is linear) ----
// krm[b,w,e] = mean_h key_row[b,h,w,e]
__global__ __launch_bounds__(256) void mean_h_kernel(const float* __restrict__ kr,
                                                     float* __restrict__ out) {
    int i = blockIdx.x * 256 + threadIdx.x;     // (b,w,e), B*W*E = 262144
    int e = i & (E_ - 1);
    int w = (i >> 8) & (W_ - 1);
    int b = i >> 15;
    const float* p = kr + ((size_t)b * H_ * W_ + w) * E_ + e;
    float s = 0.f;
    for (int h = 0; h < H_; ++h) s += p[(size_t)h * W_ * E_];
    out[i] = s * (1.0f / H_);
}
// kcm[b,h,e] = mean_w key_col[b,h,w,e]
__global__ __launch_bounds__(256) void mean_w_kernel(const float* __restrict__ kc,
                                                     float* __restrict__ out) {
    int i = blockIdx.x * 256 + threadIdx.x;     // (b,h,e)
    int e = i & (E_ - 1);
    int h = (i >> 8) & (H_ - 1);
    int b = i >> 15;
    const float* p = kc + ((size_t)(b * H_ + h) * W_) * E_ + e;
    float s = 0.f;
    for (int w = 0; w < W_; ++w) s += p[(size_t)w * E_];
    out[i] = s * (1.0f / W_);
}

// ---------------- generic 256-K / 256-N GEMM:  C = scale*(A @ Wt^T + bias) -----
__device__ __forceinline__ void load4f(const float* p, float* v) {
    float4 t = *(const float4*)p;
    v[0] = t.x; v[1] = t.y; v[2] = t.z; v[3] = t.w;
}
__device__ __forceinline__ void store4(float* p, float a, float b, float c, float d) {
    float4 t; t.x = a; t.y = b; t.z = c; t.w = d;
    *(float4*)p = t;
}
__device__ __forceinline__ void store4(ushort_t* p, float a, float b, float c, float d) {
    ushort4 t; t.x = f2bf(a); t.y = f2bf(b); t.z = f2bf(c); t.w = f2bf(d);
    *(ushort4*)p = t;
}

template <typename TC>
__global__ __launch_bounds__(256) void gemm256(const float* __restrict__ A,
                                               const float* __restrict__ Wt,   // (256,256) row-major, C[m,n]=sum_k A[m,k]*Wt[n,k]
                                               const float* __restrict__ bias, // (256,)
                                               TC* __restrict__ C, int M, float scale) {
    __shared__ __align__(16) float As[16][64];
    __shared__ __align__(16) float Bs[16][64];
    const int m0 = blockIdx.x * 64;
    const int n0 = blockIdx.y * 64;
    const int tid = threadIdx.x;
    const int lr = tid >> 2;           // 0..63
    const int lk = (tid & 3) << 2;     // 0,4,8,12
    const int tx = tid & 15, ty = tid >> 4;
    float acc[4][4] = {{0.f}};

    for (int k0 = 0; k0 < E_; k0 += 16) {
        float av[4], wv[4];
        load4f(A + (size_t)(m0 + lr) * E_ + k0 + lk, av);
        load4f(Wt + (size_t)(n0 + lr) * E_ + k0 + lk, wv);
        As[lk + 0][lr] = av[0]; As[lk + 1][lr] = av[1];
        As[lk + 2][lr] = av[2]; As[lk + 3][lr] = av[3];
        Bs[lk + 0][lr] = wv[0]; Bs[lk + 1][lr] = wv[1];
        Bs[lk + 2][lr] = wv[2]; Bs[lk + 3][lr] = wv[3];
        __syncthreads();
#pragma unroll
        for (int k = 0; k < 16; ++k) {
            float a[4], b[4];
            load4f(&As[k][ty << 2], a);
            load4f(&Bs[k][tx << 2], b);
#pragma unroll
            for (int i = 0; i < 4; ++i)
#pragma unroll
                for (int j = 0; j < 4; ++j) acc[i][j] += a[i] * b[j];
        }
        __syncthreads();
    }
    float bv[4];
    load4f(bias + n0 + (tx << 2), bv);
#pragma unroll
    for (int i = 0; i < 4; ++i) {
        TC* cp = C + (size_t)(m0 + (ty << 2) + i) * E_ + n0 + (tx << 2);
        store4(cp, scale * (acc[i][0] + bv[0]), scale * (acc[i][1] + bv[1]),
                   scale * (acc[i][2] + bv[2]), scale * (acc[i][3] + bv[3]));
    }
}

// ---------------- scores + softmax over 128 keys -------------------------------
// a[b,n,l,s] = softmax_s( sum_c q[b,l,n*32+c] * k[b,s,n*32+c] )
__global__ __launch_bounds__(128) void scores_kernel(const float* __restrict__ q,
                                                     const float* __restrict__ k,
                                                     float* __restrict__ a) {
    int blk = blockIdx.x;                 // = (b*NH+n)*L + l
    int l = blk & (L_ - 1);
    int n = (blk >> 9) & (NH_ - 1);
    int b = blk >> 12;
    int tid = threadIdx.x;                // 0..127 = s
    __shared__ float qs[32];
    __shared__ float red[128];
    if (tid < 32) qs[tid] = q[((size_t)b * L_ + l) * E_ + n * HD_ + tid];
    __syncthreads();
    const float* kp = k + ((size_t)b * 128 + tid) * E_ + n * HD_;
    float dot = 0.f;
#pragma unroll
    for (int c = 0; c < HD_; ++c) dot += qs[c] * kp[c];
    red[tid] = dot;
    __syncthreads();
    for (int off = 64; off > 0; off >>= 1) {
        if (tid < off) { float o = red[tid + off]; if (o > red[tid]) red[tid] = o; }
        __syncthreads();
    }
    float mx = red[0];
    __syncthreads();
    float ex = __expf(dot - mx);
    red[tid] = ex;
    __syncthreads();
    for (int off = 64; off > 0; off >>= 1) {
        if (tid < off) red[tid] += red[tid + off];
        __syncthreads();
    }
    a[(size_t)blk * 128 + tid] = ex * (1.0f / red[0]);
}

// ---------------- attention core ------------------------------------------------
// attn[l,b, n*32+c] = sum_h a_col[b,n,l,h] * sum_w a_row[b,n,l,w] * v[b,h,w,n*32+c]
__global__ __launch_bounds__(256) void core_kernel(const float* __restrict__ a_row,
                                                   const float* __restrict__ a_col,
                                                   const ushort_t* __restrict__ v,
                                                   float* __restrict__ attn) {
    int blk = blockIdx.x;                 // = (b*NH+n)*L + l
    int l = blk & (L_ - 1);
    int n = (blk >> 9) & (NH_ - 1);
    int b = blk >> 12;
    int tid = threadIdx.x;
    __shared__ float ar[W_], ac[H_];
    __shared__ float redx[256], redy[256], redz[256], redw[256];
    size_t base = (size_t)blk * 128;
    if (tid < 128) ar[tid] = a_row[base + tid];
    else           ac[tid - 128] = a_col[base + (tid - 128)];
    __syncthreads();

    int hg = tid >> 3;                    // 0..31
    int cq = tid & 7;                     // 0..7  -> c = cq*4
    const ushort_t* vp = v + (size_t)b * H_ * W_ * E_ + n * HD_ + (cq << 2);
    float ax = 0.f, ay = 0.f, az = 0.f, aw = 0.f;
    for (int h = hg; h < H_; h += 32) {
        const ushort_t* vph = vp + (size_t)h * W_ * E_;
        float sx = 0.f, sy = 0.f, sz = 0.f, sw = 0.f;
#pragma unroll 4
        for (int w = 0; w < W_; ++w) {
            ushort4 u = *(const ushort4*)&vph[(size_t)w * E_];
            float aval = ar[w];
            sx += aval * bf2f(u.x);
            sy += aval * bf2f(u.y);
            sz += aval * bf2f(u.z);
            sw += aval * bf2f(u.w);
        }
        float cv = ac[h];
        ax += cv * sx; ay += cv * sy; az += cv * sz; aw += cv * sw;
    }
    redx[tid] = ax; redy[tid] = ay; redz[tid] = az; redw[tid] = aw;
    __syncthreads();
    for (int off = 128; off >= 8; off >>= 1) {
        if (tid < off) {
            redx[tid] += redx[tid + off];
            redy[tid] += redy[tid + off];
            redz[tid] += redz[tid + off];
            redw[tid] += redw[tid + off];
        }
        __syncthreads();
    }
    if (tid < 8) {
        float* op = attn + ((size_t)l * B_ + b) * E_ + n * HD_ + (tid << 2);
        store4(op, redx[tid], redy[tid], redz[tid], redw[tid]);
    }
}

// ---------------- launch --------------------------------------------------------
extern "C" void kernel_launch(void* const* d_in, const int* in_sizes, int n_in,
                              void* d_out, int out_size, void* d_ws, size_t ws_size,
                              hipStream_t stream) {
    const float* query_row = (const float*)d_in[0];
    const float* query_col = (const float*)d_in[1];
    const float* key_row   = (const float*)d_in[2];
    const float* key_col   = (const float*)d_in[3];
    const float* value     = (const float*)d_in[4];
    const float* ipw       = (const float*)d_in[5];   // (1280,256)
    const float* ipb       = (const float*)d_in[6];   // (1280,)
    const float* opw       = (const float*)d_in[7];   // (256,256)
    const float* opb       = (const float*)d_in[8];   // (256,)
    float* out = (float*)d_out;

    char* ws = (char*)d_ws;
    float* q_row_s = (float*)ws;  ws += (size_t)4096 * 256 * 4;
    float* q_col_s = (float*)ws;  ws += (size_t)4096 * 256 * 4;
    float* krm     = (float*)ws;  ws += (size_t)262144 * 4;
    float* kcm     = (float*)ws;  ws += (size_t)262144 * 4;
    float* k_row   = (float*)ws;  ws += (size_t)262144 * 4;
    float* k_col   = (float*)ws;  ws += (size_t)262144 * 4;
    ushort_t* vbuf = (ushort_t*)ws; ws += (size_t)33554432 * 2;
    float* a_row   = (float*)ws;  ws += (size_t)4194304 * 4;
    float* a_col   = (float*)ws;  ws += (size_t)4194304 * 4;
    float* attn    = (float*)ws;  ws += (size_t)4096 * 256 * 4;

    const float scale = 0.17677669529663687f;   // HD^-0.5

    mean_h_kernel<<<1024, 256, 0, stream>>>(key_row, krm);
    mean_w_kernel<<<1024, 256, 0, stream>>>(key_col, kcm);

    gemm256<float><<<dim3(64, 4), 256, 0, stream>>>(query_row, ipw + 0 * 65536, ipb + 0,    q_row_s, 4096, scale);
    gemm256<float><<<dim3(64, 4), 256, 0, stream>>>(query_col, ipw + 1 * 65536, ipb + 256,  q_col_s, 4096, scale);
    gemm256<float><<<dim3(16, 4), 256, 0, stream>>>(krm,       ipw + 2 * 65536, ipb + 512,  k_row,   1024, 1.0f);
    gemm256<float><<<dim3(16, 4), 256, 0, stream>>>(kcm,       ipw + 3 * 65536, ipb + 768,  k_col,   1024, 1.0f);
    gemm256<ushort_t><<<dim3(2048, 4), 256, 0, stream>>>(value, ipw + 4 * 65536, ipb + 1024, vbuf, 131072, 1.0f);

    scores_kernel<<<32768, 128, 0, stream>>>(q_row_s, k_row, a_row);
    scores_kernel<<<32768, 128, 0, stream>>>(q_col_s, k_col, a_col);

    core_kernel<<<32768, 256, 0, stream>>>(a_row, a_col, vbuf, attn);

    gemm256<float><<<dim3(64, 4), 256, 0, stream>>>(attn, opw, opb, out, 4096, 1.0f);
}

// Round 3
// 801.647 us; speedup vs baseline: 3.5852x; 3.5852x over previous
//
#include <hip/hip_runtime.h>
#include <stdint.h>

#define B_  8
#define L_  512
#define E_  256
#define H_  128
#define W_  128
#define NH_ 8
#define HD_ 32

typedef unsigned short ushort_t;
typedef __attribute__((ext_vector_type(8))) short bf16x8;
typedef __attribute__((ext_vector_type(4))) float f32x4;

__device__ __forceinline__ float bf2f(ushort_t u) {
    union { unsigned int i; float f; } x;
    x.i = ((unsigned int)u) << 16;
    return x.f;
}
__device__ __forceinline__ ushort_t f2bf(float f) {
    union { float f; unsigned int i; } x;
    x.f = f;
    unsigned int r = x.i + 0x7FFFu + ((x.i >> 16) & 1u);
    return (ushort_t)(r >> 16);
}

// ---------------- mean reductions (fused before projection; mean is linear) ----
__global__ __launch_bounds__(256) void mean_h_kernel(const float* __restrict__ kr,
                                                     float* __restrict__ out) {
    int i = blockIdx.x * 256 + threadIdx.x;     // (b,w,e)
    int e = i & (E_ - 1);
    int w = (i >> 8) & (W_ - 1);
    int b = i >> 15;
    const float* p = kr + ((size_t)b * H_ * W_ + w) * E_ + e;
    float s = 0.f;
    for (int h = 0; h < H_; ++h) s += p[(size_t)h * W_ * E_];
    out[i] = s * (1.0f / H_);
}
__global__ __launch_bounds__(256) void mean_w_kernel(const float* __restrict__ kc,
                                                     float* __restrict__ out) {
    int i = blockIdx.x * 256 + threadIdx.x;     // (b,h,e)
    int e = i & (E_ - 1);
    int h = (i >> 8) & (H_ - 1);
    int b = i >> 15;
    const float* p = kc + ((size_t)(b * H_ + h) * W_) * E_ + e;
    float s = 0.f;
    for (int w = 0; w < W_; ++w) s += p[(size_t)w * E_];
    out[i] = s * (1.0f / W_);
}

// ---------------- fp32 tile GEMM (small projections):  C = scale*(A @ Wt^T + b) --
__device__ __forceinline__ void load4f(const float* p, float* v) {
    float4 t = *(const float4*)p;
    v[0] = t.x; v[1] = t.y; v[2] = t.z; v[3] = t.w;
}
__device__ __forceinline__ void store4(float* p, float a, float b, float c, float d) {
    float4 t; t.x = a; t.y = b; t.z = c; t.w = d;
    *(float4*)p = t;
}

__global__ __launch_bounds__(256) void gemm256(const float* __restrict__ A,
                                               const float* __restrict__ Wt,
                                               const float* __restrict__ bias,
                                               float* __restrict__ C, int M, float scale) {
    __shared__ __align__(16) float As[16][64];
    __shared__ __align__(16) float Bs[16][64];
    const int m0 = blockIdx.x * 64;
    const int n0 = blockIdx.y * 64;
    const int tid = threadIdx.x;
    const int lr = tid >> 2;
    const int lk = (tid & 3) << 2;
    const int tx = tid & 15, ty = tid >> 4;
    float acc[4][4] = {{0.f}};

    for (int k0 = 0; k0 < E_; k0 += 16) {
        float av[4], wv[4];
        load4f(A + (size_t)(m0 + lr) * E_ + k0 + lk, av);
        load4f(Wt + (size_t)(n0 + lr) * E_ + k0 + lk, wv);
        As[lk + 0][lr] = av[0]; As[lk + 1][lr] = av[1];
        As[lk + 2][lr] = av[2]; As[lk + 3][lr] = av[3];
        Bs[lk + 0][lr] = wv[0]; Bs[lk + 1][lr] = wv[1];
        Bs[lk + 2][lr] = wv[2]; Bs[lk + 3][lr] = wv[3];
        __syncthreads();
#pragma unroll
        for (int k = 0; k < 16; ++k) {
            float a[4], b[4];
            load4f(&As[k][ty << 2], a);
            load4f(&Bs[k][tx << 2], b);
#pragma unroll
            for (int i = 0; i < 4; ++i)
#pragma unroll
                for (int j = 0; j < 4; ++j) acc[i][j] += a[i] * b[j];
        }
        __syncthreads();
    }
    float bv[4];
    load4f(bias + n0 + (tx << 2), bv);
#pragma unroll
    for (int i = 0; i < 4; ++i) {
        float* cp = C + (size_t)(m0 + (ty << 2) + i) * E_ + n0 + (tx << 2);
        store4(cp, scale * (acc[i][0] + bv[0]), scale * (acc[i][1] + bv[1]),
                   scale * (acc[i][2] + bv[2]), scale * (acc[i][3] + bv[3]));
    }
}

// ---------------- value projection, MFMA bf16, TRANSPOSED output ----------------
// v_t[b][e][h][w] = (value @ Wv^T + bias)[b,h,w,e],  m = b*16384 + h*128 + w
#define KP_ 264   // 256 + 8 pad (bf16 elems) -> 2-way-free LDS banks
__global__ __launch_bounds__(256) void vproj_mfma(const float* __restrict__ Ag,
                                                  const float* __restrict__ Wg,
                                                  const float* __restrict__ bias,
                                                  ushort_t* __restrict__ v_t) {
    __shared__ ushort_t A_lds[64 * KP_];
    __shared__ ushort_t W_lds[64 * KP_];
    const int m0 = blockIdx.x * 64;
    const int n0 = blockIdx.y * 64;
    const int tid  = threadIdx.x;
    const int lane = tid & 63;
    const int wv   = tid >> 6;
    const int quad = lane >> 4;
    const int lc   = lane & 15;

    // stage A rows (value) and W rows, fp32 -> bf16
    {
        int r = tid >> 2, kq = (tid & 3) * 64;
        const float* sa = Ag + (size_t)(m0 + r) * 256 + kq;
        const float* sw = Wg + (size_t)(n0 + r) * 256 + kq;
        ushort_t* da = A_lds + r * KP_ + kq;
        ushort_t* dw = W_lds + r * KP_ + kq;
#pragma unroll
        for (int j = 0; j < 16; ++j) {
            float4 f = *(const float4*)(sa + j * 4);
            ushort4 u; u.x = f2bf(f.x); u.y = f2bf(f.y); u.z = f2bf(f.z); u.w = f2bf(f.w);
            *(ushort4*)(da + j * 4) = u;
            float4 g = *(const float4*)(sw + j * 4);
            ushort4 v; v.x = f2bf(g.x); v.y = f2bf(g.y); v.z = f2bf(g.z); v.w = f2bf(g.w);
            *(ushort4*)(dw + j * 4) = v;
        }
    }
    __syncthreads();

    const int msub = (wv & 1) * 32;
    const int nsub = (wv >> 1) * 32;
    f32x4 acc[2][2] = {{{0.f,0.f,0.f,0.f},{0.f,0.f,0.f,0.f}},
                       {{0.f,0.f,0.f,0.f},{0.f,0.f,0.f,0.f}}};
#pragma unroll
    for (int kc = 0; kc < 8; ++kc) {
        const int ko = kc * 32 + quad * 8;
        bf16x8 a0 = *(const bf16x8*)(A_lds + (msub + lc) * KP_ + ko);
        bf16x8 a1 = *(const bf16x8*)(A_lds + (msub + 16 + lc) * KP_ + ko);
        bf16x8 b0 = *(const bf16x8*)(W_lds + (nsub + lc) * KP_ + ko);
        bf16x8 b1 = *(const bf16x8*)(W_lds + (nsub + 16 + lc) * KP_ + ko);
        acc[0][0] = __builtin_amdgcn_mfma_f32_16x16x32_bf16(a0, b0, acc[0][0], 0, 0, 0);
        acc[0][1] = __builtin_amdgcn_mfma_f32_16x16x32_bf16(a0, b1, acc[0][1], 0, 0, 0);
        acc[1][0] = __builtin_amdgcn_mfma_f32_16x16x32_bf16(a1, b0, acc[1][0], 0, 0, 0);
        acc[1][1] = __builtin_amdgcn_mfma_f32_16x16x32_bf16(a1, b1, acc[1][1], 0, 0, 0);
    }

    float bv0 = bias[n0 + nsub + lc];
    float bv1 = bias[n0 + nsub + 16 + lc];
    __syncthreads();                       // done reading A_lds/W_lds
    ushort_t* out_lds = A_lds;             // reuse as [64 n][80 m]
#pragma unroll
    for (int mi = 0; mi < 2; ++mi)
#pragma unroll
        for (int nj = 0; nj < 2; ++nj) {
            f32x4 v = acc[mi][nj];
            float bb = nj ? bv1 : bv0;
            int nl = nsub + nj * 16 + lc;
            int mb = msub + mi * 16 + quad * 4;
            ushort4 u;
            u.x = f2bf(v[0] + bb); u.y = f2bf(v[1] + bb);
            u.z = f2bf(v[2] + bb); u.w = f2bf(v[3] + bb);
            *(ushort4*)(out_lds + nl * 80 + mb) = u;
        }
    __syncthreads();
    {
        int nl = tid >> 2, mo = (tid & 3) * 16;
        int bb = m0 >> 14;
        int ml = (m0 & 16383) + mo;
        ushort_t* dst = v_t + (size_t)bb * 4194304 + (size_t)(n0 + nl) * 16384 + ml;
        const ushort_t* s = out_lds + nl * 80 + mo;
        *(uint4*)dst = *(const uint4*)s;
        *(uint4*)(dst + 8) = *(const uint4*)(s + 8);
    }
}

// ---------------- scores + softmax over 128 keys -------------------------------
__global__ __launch_bounds__(128) void scores_kernel(const float* __restrict__ q,
                                                     const float* __restrict__ k,
                                                     float* __restrict__ a) {
    int blk = blockIdx.x;                 // = (b*NH+n)*L + l
    int l = blk & (L_ - 1);
    int n = (blk >> 9) & (NH_ - 1);
    int b = blk >> 12;
    int tid = threadIdx.x;                // s
    __shared__ float qs[32];
    __shared__ float red[128];
    if (tid < 32) qs[tid] = q[((size_t)b * L_ + l) * E_ + n * HD_ + tid];
    __syncthreads();
    const float* kp = k + ((size_t)b * 128 + tid) * E_ + n * HD_;
    float dot = 0.f;
#pragma unroll
    for (int c = 0; c < HD_; ++c) dot += qs[c] * kp[c];
    red[tid] = dot;
    __syncthreads();
    for (int off = 64; off > 0; off >>= 1) {
        if (tid < off) { float o = red[tid + off]; if (o > red[tid]) red[tid] = o; }
        __syncthreads();
    }
    float mx = red[0];
    __syncthreads();
    float ex = __expf(dot - mx);
    red[tid] = ex;
    __syncthreads();
    for (int off = 64; off > 0; off >>= 1) {
        if (tid < off) red[tid] += red[tid + off];
        __syncthreads();
    }
    a[(size_t)blk * 128 + tid] = ex * (1.0f / red[0]);
}

// ---------------- fused axial attention core, MFMA bf16 -------------------------
// block = (b, n, lt): out[l, c] = sum_h ac[l,h] * (ar[l,:] @ V_h[:, c])
#define ARP 136
#define VBP 136
__global__ __launch_bounds__(256) void core_mfma(const float* __restrict__ a_row,
                                                 const float* __restrict__ a_col,
                                                 const ushort_t* __restrict__ v_t,
                                                 float* __restrict__ attn) {
    __shared__ ushort_t ar_lds[64 * ARP];          // [l_local][w] bf16
    __shared__ float    ac_lds[128 * 64];          // [h][l_local] fp32
    __shared__ ushort_t vb_lds[2][32 * VBP];       // [c][w] bf16

    const int blk = blockIdx.x;                    // lt*64 + (b*8+n): siblings share XCD
    const int lt = blk >> 6;
    const int bn = blk & 63;
    const int n  = bn & 7;
    const int b  = bn >> 3;
    const int tid  = threadIdx.x;
    const int lane = tid & 63;
    const int wv   = tid >> 6;
    const int quad = lane >> 4;
    const int lc   = lane & 15;

    const size_t abase = ((size_t)(b * NH_ + n) * L_ + lt * 64) * 128;
    // ar -> bf16 LDS
    {
        int r = tid >> 2, wq = (tid & 3) * 32;
        const float* src = a_row + abase + (size_t)r * 128 + wq;
        ushort_t* dst = ar_lds + r * ARP + wq;
#pragma unroll
        for (int j = 0; j < 8; ++j) {
            float4 f = *(const float4*)(src + j * 4);
            ushort4 u; u.x = f2bf(f.x); u.y = f2bf(f.y); u.z = f2bf(f.z); u.w = f2bf(f.w);
            *(ushort4*)(dst + j * 4) = u;
        }
    }
    // ac -> fp32 LDS transposed [h][l]
    {
        int r = tid >> 2, hq = (tid & 3) * 32;
        const float* src = a_col + abase + (size_t)r * 128 + hq;
#pragma unroll
        for (int j = 0; j < 8; ++j) {
            float4 f = *(const float4*)(src + j * 4);
            int h0 = hq + j * 4;
            ac_lds[(h0 + 0) * 64 + r] = f.x;
            ac_lds[(h0 + 1) * 64 + r] = f.y;
            ac_lds[(h0 + 2) * 64 + r] = f.z;
            ac_lds[(h0 + 3) * 64 + r] = f.w;
        }
    }

    const ushort_t* vtb = v_t + (size_t)b * 4194304 + (size_t)(n * 32) * 16384;
    const int sc = tid >> 3;            // 0..31 (c)
    const int sw = (tid & 7) * 16;      // w chunk
#define STAGE(hh, bu)                                                              \
    {                                                                              \
        const ushort_t* s = vtb + (size_t)sc * 16384 + (hh) * 128 + sw;            \
        ushort_t* d = vb_lds[bu] + sc * VBP + sw;                                  \
        *(uint4*)d = *(const uint4*)s;                                             \
        *(uint4*)(d + 8) = *(const uint4*)(s + 8);                                 \
    }

    __syncthreads();                    // ar/ac ready
    bf16x8 A[4];
#pragma unroll
    for (int kc = 0; kc < 4; ++kc)
        A[kc] = *(const bf16x8*)(ar_lds + (wv * 16 + lc) * ARP + kc * 32 + quad * 8);

    f32x4 acc0 = {0.f,0.f,0.f,0.f}, acc1 = {0.f,0.f,0.f,0.f};
    STAGE(0, 0);
    for (int h = 0; h < 128; ++h) {
        __syncthreads();                // stage(h) visible; prev compute done
        if (h + 1 < 128) STAGE(h + 1, (h + 1) & 1);
        const ushort_t* vb = vb_lds[h & 1];
        f32x4 t0 = {0.f,0.f,0.f,0.f}, t1 = {0.f,0.f,0.f,0.f};
#pragma unroll
        for (int kc = 0; kc < 4; ++kc) {
            const int ko = kc * 32 + quad * 8;
            bf16x8 b0 = *(const bf16x8*)(vb + lc * VBP + ko);
            bf16x8 b1 = *(const bf16x8*)(vb + (16 + lc) * VBP + ko);
            t0 = __builtin_amdgcn_mfma_f32_16x16x32_bf16(A[kc], b0, t0, 0, 0, 0);
            t1 = __builtin_amdgcn_mfma_f32_16x16x32_bf16(A[kc], b1, t1, 0, 0, 0);
        }
        const float4 acv = *(const float4*)(ac_lds + h * 64 + wv * 16 + quad * 4);
        acc0[0] += acv.x * t0[0]; acc1[0] += acv.x * t1[0];
        acc0[1] += acv.y * t0[1]; acc1[1] += acv.y * t1[1];
        acc0[2] += acv.z * t0[2]; acc1[2] += acv.z * t1[2];
        acc0[3] += acv.w * t0[3]; acc1[3] += acv.w * t1[3];
    }

    const int row0 = wv * 16 + quad * 4;
#pragma unroll
    for (int r = 0; r < 4; ++r) {
        size_t o = ((size_t)(lt * 64 + row0 + r) * B_ + b) * E_ + n * HD_ + lc;
        attn[o] = acc0[r];
        attn[o + 16] = acc1[r];
    }
#undef STAGE
}

// ---------------- launch --------------------------------------------------------
extern "C" void kernel_launch(void* const* d_in, const int* in_sizes, int n_in,
                              void* d_out, int out_size, void* d_ws, size_t ws_size,
                              hipStream_t stream) {
    const float* query_row = (const float*)d_in[0];
    const float* query_col = (const float*)d_in[1];
    const float* key_row   = (const float*)d_in[2];
    const float* key_col   = (const float*)d_in[3];
    const float* value     = (const float*)d_in[4];
    const float* ipw       = (const float*)d_in[5];
    const float* ipb       = (const float*)d_in[6];
    const float* opw       = (const float*)d_in[7];
    const float* opb       = (const float*)d_in[8];
    float* out = (float*)d_out;

    char* ws = (char*)d_ws;
    float* q_row_s = (float*)ws;  ws += (size_t)4096 * 256 * 4;
    float* q_col_s = (float*)ws;  ws += (size_t)4096 * 256 * 4;
    float* krm     = (float*)ws;  ws += (size_t)262144 * 4;
    float* kcm     = (float*)ws;  ws += (size_t)262144 * 4;
    float* k_row   = (float*)ws;  ws += (size_t)262144 * 4;
    float* k_col   = (float*)ws;  ws += (size_t)262144 * 4;
    ushort_t* v_t  = (ushort_t*)ws; ws += (size_t)33554432 * 2;   // [B][256][128][128]
    float* a_row   = (float*)ws;  ws += (size_t)4194304 * 4;
    float* a_col   = (float*)ws;  ws += (size_t)4194304 * 4;
    float* attn    = (float*)ws;  ws += (size_t)4096 * 256 * 4;

    const float scale = 0.17677669529663687f;   // HD^-0.5

    mean_h_kernel<<<1024, 256, 0, stream>>>(key_row, krm);
    mean_w_kernel<<<1024, 256, 0, stream>>>(key_col, kcm);

    gemm256<<<dim3(64, 4), 256, 0, stream>>>(query_row, ipw + 0 * 65536, ipb + 0,    q_row_s, 4096, scale);
    gemm256<<<dim3(64, 4), 256, 0, stream>>>(query_col, ipw + 1 * 65536, ipb + 256,  q_col_s, 4096, scale);
    gemm256<<<dim3(16, 4), 256, 0, stream>>>(krm,       ipw + 2 * 65536, ipb + 512,  k_row,   1024, 1.0f);
    gemm256<<<dim3(16, 4), 256, 0, stream>>>(kcm,       ipw + 3 * 65536, ipb + 768,  k_col,   1024, 1.0f);

    vproj_mfma<<<dim3(2048, 4), 256, 0, stream>>>(value, ipw + 4 * 65536, ipb + 1024, v_t);

    scores_kernel<<<32768, 128, 0, stream>>>(q_row_s, k_row, a_row);
    scores_kernel<<<32768, 128, 0, stream>>>(q_col_s, k_col, a_col);

    core_mfma<<<512, 256, 0, stream>>>(a_row, a_col, v_t, attn);

    gemm256<<<dim3(64, 4), 256, 0, stream>>>(attn, opw, opb, out, 4096, 1.0f);
}

// Round 4
// 688.087 us; speedup vs baseline: 4.1769x; 1.1650x over previous
//
#include <hip/hip_runtime.h>
#include <stdint.h>

#define B_  8
#define L_  512
#define E_  256
#define H_  128
#define W_  128
#define NH_ 8
#define HD_ 32

typedef unsigned short ushort_t;
typedef __attribute__((ext_vector_type(8))) short bf16x8;
typedef __attribute__((ext_vector_type(4))) float f32x4;

__device__ __forceinline__ float bf2f(ushort_t u) {
    union { unsigned int i; float f; } x;
    x.i = ((unsigned int)u) << 16;
    return x.f;
}
__device__ __forceinline__ ushort_t f2bf(float f) {
    union { float f; unsigned int i; } x;
    x.f = f;
    unsigned int r = x.i + 0x7FFFu + ((x.i >> 16) & 1u);
    return (ushort_t)(r >> 16);
}

// ---------------- mean reductions (mean is linear; project after) --------------
__global__ __launch_bounds__(256) void mean_h_kernel(const float* __restrict__ kr,
                                                     float* __restrict__ out) {
    int i = blockIdx.x * 256 + threadIdx.x;     // (b,w,e)
    int e = i & (E_ - 1);
    int w = (i >> 8) & (W_ - 1);
    int b = i >> 15;
    const float* p = kr + ((size_t)b * H_ * W_ + w) * E_ + e;
    float s = 0.f;
    for (int h = 0; h < H_; ++h) s += p[(size_t)h * W_ * E_];
    out[i] = s * (1.0f / H_);
}
__global__ __launch_bounds__(256) void mean_w_kernel(const float* __restrict__ kc,
                                                     float* __restrict__ out) {
    int i = blockIdx.x * 256 + threadIdx.x;     // (b,h,e)
    int e = i & (E_ - 1);
    int h = (i >> 8) & (H_ - 1);
    int b = i >> 15;
    const float* p = kc + ((size_t)(b * H_ + h) * W_) * E_ + e;
    float s = 0.f;
    for (int w = 0; w < W_; ++w) s += p[(size_t)w * E_];
    out[i] = s * (1.0f / W_);
}

// ---------------- fp32 tile GEMM (projections):  C = scale*(A @ Wt^T + b) ------
__device__ __forceinline__ void load4f(const float* p, float* v) {
    float4 t = *(const float4*)p;
    v[0] = t.x; v[1] = t.y; v[2] = t.z; v[3] = t.w;
}
__device__ __forceinline__ void store4(float* p, float a, float b, float c, float d) {
    float4 t; t.x = a; t.y = b; t.z = c; t.w = d;
    *(float4*)p = t;
}

__global__ __launch_bounds__(256) void gemm256(const float* __restrict__ A,
                                               const float* __restrict__ Wt,
                                               const float* __restrict__ bias,
                                               float* __restrict__ C, int M, float scale) {
    __shared__ __align__(16) float As[16][64];
    __shared__ __align__(16) float Bs[16][64];
    const int m0 = blockIdx.x * 64;
    const int n0 = blockIdx.y * 64;
    const int tid = threadIdx.x;
    const int lr = tid >> 2;
    const int lk = (tid & 3) << 2;
    const int tx = tid & 15, ty = tid >> 4;
    float acc[4][4] = {{0.f}};

    for (int k0 = 0; k0 < E_; k0 += 16) {
        float av[4], wv[4];
        load4f(A + (size_t)(m0 + lr) * E_ + k0 + lk, av);
        load4f(Wt + (size_t)(n0 + lr) * E_ + k0 + lk, wv);
        As[lk + 0][lr] = av[0]; As[lk + 1][lr] = av[1];
        As[lk + 2][lr] = av[2]; As[lk + 3][lr] = av[3];
        Bs[lk + 0][lr] = wv[0]; Bs[lk + 1][lr] = wv[1];
        Bs[lk + 2][lr] = wv[2]; Bs[lk + 3][lr] = wv[3];
        __syncthreads();
#pragma unroll
        for (int k = 0; k < 16; ++k) {
            float a[4], b[4];
            load4f(&As[k][ty << 2], a);
            load4f(&Bs[k][tx << 2], b);
#pragma unroll
            for (int i = 0; i < 4; ++i)
#pragma unroll
                for (int j = 0; j < 4; ++j) acc[i][j] += a[i] * b[j];
        }
        __syncthreads();
    }
    float bv[4];
    load4f(bias + n0 + (tx << 2), bv);
#pragma unroll
    for (int i = 0; i < 4; ++i) {
        float* cp = C + (size_t)(m0 + (ty << 2) + i) * E_ + n0 + (tx << 2);
        store4(cp, scale * (acc[i][0] + bv[0]), scale * (acc[i][1] + bv[1]),
                   scale * (acc[i][2] + bv[2]), scale * (acc[i][3] + bv[3]));
    }
}

// ---------------- W_v -> bf16 ---------------------------------------------------
__global__ __launch_bounds__(256) void wconv_kernel(const float* __restrict__ w,
                                                    ushort_t* __restrict__ wbf) {
    int i = (blockIdx.x * 256 + threadIdx.x) * 4;
    float4 f = *(const float4*)(w + i);
    ushort4 u;
    u.x = f2bf(f.x); u.y = f2bf(f.y); u.z = f2bf(f.z); u.w = f2bf(f.w);
    *(ushort4*)(wbf + i) = u;
}

// ---------------- value projection, MFMA bf16, transposed output ---------------
// v_t[b][e][m],  m = h*128+w.  A-op = W rows (e), B-op = value rows (m):
// D[row=quad*4+reg -> e][col=lc -> m]  => lane-contiguous m, direct stores.
#define KP_ 264
__global__ __launch_bounds__(256) void vproj_mfma(const float* __restrict__ Ag,
                                                  const ushort_t* __restrict__ Wbf,
                                                  const float* __restrict__ bias,
                                                  ushort_t* __restrict__ v_t) {
    __shared__ ushort_t A_lds[64 * KP_];         // 33.7 KB
    const int m0 = blockIdx.x * 64;
    const int tid = threadIdx.x, lane = tid & 63, wv = tid >> 6;
    const int quad = lane >> 4, lc = lane & 15;
    {   // stage 64 value rows fp32 -> bf16
        int r = tid >> 2, kq = (tid & 3) * 64;
        const float* sa = Ag + (size_t)(m0 + r) * 256 + kq;
        ushort_t* da = A_lds + r * KP_ + kq;
#pragma unroll
        for (int j = 0; j < 16; ++j) {
            float4 f = *(const float4*)(sa + j * 4);
            ushort4 u;
            u.x = f2bf(f.x); u.y = f2bf(f.y); u.z = f2bf(f.z); u.w = f2bf(f.w);
            *(ushort4*)(da + j * 4) = u;
        }
    }
    __syncthreads();
    bf16x8 bfr[8];
#pragma unroll
    for (int kc = 0; kc < 8; ++kc)
        bfr[kc] = *(const bf16x8*)(A_lds + (wv * 16 + lc) * KP_ + kc * 32 + quad * 8);

    const int b = m0 >> 14;
    const int ml = (m0 & 16383) + wv * 16 + lc;
    ushort_t* vtb = v_t + (size_t)b * 4194304 + ml;

    for (int g = 0; g < 4; ++g) {
        f32x4 acc[4];
#pragma unroll
        for (int t = 0; t < 4; ++t) { acc[t][0]=0.f; acc[t][1]=0.f; acc[t][2]=0.f; acc[t][3]=0.f; }
#pragma unroll
        for (int kc = 0; kc < 8; ++kc) {
#pragma unroll
            for (int t = 0; t < 4; ++t) {
                bf16x8 af = *(const bf16x8*)(Wbf + (size_t)(g * 64 + t * 16 + lc) * 256 + kc * 32 + quad * 8);
                acc[t] = __builtin_amdgcn_mfma_f32_16x16x32_bf16(af, bfr[kc], acc[t], 0, 0, 0);
            }
        }
#pragma unroll
        for (int t = 0; t < 4; ++t) {
            int e0 = g * 64 + t * 16 + quad * 4;
            float4 b4 = *(const float4*)(bias + e0);
            vtb[(size_t)(e0 + 0) * 16384] = f2bf(acc[t][0] + b4.x);
            vtb[(size_t)(e0 + 1) * 16384] = f2bf(acc[t][1] + b4.y);
            vtb[(size_t)(e0 + 2) * 16384] = f2bf(acc[t][2] + b4.z);
            vtb[(size_t)(e0 + 3) * 16384] = f2bf(acc[t][3] + b4.w);
        }
    }
}

// ---------------- row scores, tiled: 32 l x 128 w per block --------------------
// a[bn][l][w] = softmax_w(q_row . k_row)
__global__ __launch_bounds__(256) void scores_row(const float* __restrict__ q,
                                                  const float* __restrict__ k,
                                                  float* __restrict__ a) {
    const int lt = blockIdx.x, bn = blockIdx.y;
    const int n = bn & 7, b = bn >> 3;
    const int tid = threadIdx.x;
    __shared__ float ks[128][36];
    {   // stage k slice [128][32]
        int r = tid >> 1, c16 = (tid & 1) * 16;
        const float* src = k + ((size_t)b * 128 + r) * 256 + n * 32 + c16;
#pragma unroll
        for (int j = 0; j < 4; ++j) {
            float4 f = *(const float4*)(src + j * 4);
            ks[r][c16 + j * 4 + 0] = f.x; ks[r][c16 + j * 4 + 1] = f.y;
            ks[r][c16 + j * 4 + 2] = f.z; ks[r][c16 + j * 4 + 3] = f.w;
        }
    }
    const int ll = tid >> 3, wq = tid & 7;      // w = 8*j + wq
    float4 q4r[8];
    {
        const float* qp = q + ((size_t)b * 512 + lt * 32 + ll) * 256 + n * 32;
#pragma unroll
        for (int c4 = 0; c4 < 8; ++c4) q4r[c4] = *(const float4*)(qp + c4 * 4);
    }
    __syncthreads();
    float dots[16];
#pragma unroll
    for (int j = 0; j < 16; ++j) dots[j] = 0.f;
#pragma unroll
    for (int c4 = 0; c4 < 8; ++c4) {
        float4 q4 = q4r[c4];
#pragma unroll
        for (int j = 0; j < 16; ++j) {
            float4 k4 = *(const float4*)&ks[j * 8 + wq][c4 * 4];
            dots[j] += q4.x * k4.x + q4.y * k4.y + q4.z * k4.z + q4.w * k4.w;
        }
    }
    float mx = dots[0];
#pragma unroll
    for (int j = 1; j < 16; ++j) mx = fmaxf(mx, dots[j]);
    for (int d = 1; d < 8; d <<= 1) mx = fmaxf(mx, __shfl_xor(mx, d, 64));
    float ex[16], sm = 0.f;
#pragma unroll
    for (int j = 0; j < 16; ++j) { ex[j] = __expf(dots[j] - mx); sm += ex[j]; }
    for (int d = 1; d < 8; d <<= 1) sm += __shfl_xor(sm, d, 64);
    float inv = 1.0f / sm;
    float* ap = a + ((size_t)bn * 512 + lt * 32 + ll) * 128 + wq;
#pragma unroll
    for (int j = 0; j < 16; ++j) ap[j * 8] = ex[j] * inv;
}

// ---------------- col scores, tiled + transposed output ------------------------
// ac_t[bn][h][l] = softmax_h(q_col . k_col)
__global__ __launch_bounds__(256) void scores_col(const float* __restrict__ q,
                                                  const float* __restrict__ k,
                                                  float* __restrict__ ac_t) {
    const int lt = blockIdx.x, bn = blockIdx.y;
    const int n = bn & 7, b = bn >> 3;
    const int tid = threadIdx.x;
    __shared__ float qs[32][36];
    __shared__ float sc[128][33];
    __shared__ float mxr[8][32], smr[8][32], fin[2][32];
    {   // stage q tile [32][32]
        int r = tid >> 3, c4 = (tid & 7) * 4;
        float4 f = *(const float4*)(q + ((size_t)b * 512 + lt * 32 + r) * 256 + n * 32 + c4);
        qs[r][c4 + 0] = f.x; qs[r][c4 + 1] = f.y; qs[r][c4 + 2] = f.z; qs[r][c4 + 3] = f.w;
    }
    const int h = tid >> 1, lq = tid & 1;
    float4 kk[8];
    {
        const float* kp = k + ((size_t)b * 128 + h) * 256 + n * 32;
#pragma unroll
        for (int c4 = 0; c4 < 8; ++c4) kk[c4] = *(const float4*)(kp + c4 * 4);
    }
    __syncthreads();
    float dots[16];
#pragma unroll
    for (int j = 0; j < 16; ++j) dots[j] = 0.f;
#pragma unroll
    for (int c4 = 0; c4 < 8; ++c4) {
        float4 k4 = kk[c4];
#pragma unroll
        for (int j = 0; j < 16; ++j) {
            float4 q4 = *(const float4*)&qs[j * 2 + lq][c4 * 4];
            dots[j] += k4.x * q4.x + k4.y * q4.y + k4.z * q4.z + k4.w * q4.w;
        }
    }
#pragma unroll
    for (int j = 0; j < 16; ++j) sc[h][j * 2 + lq] = dots[j];
    __syncthreads();
    {   // per-l max over h (8 segs x 16)
        int lcol = tid & 31, seg = tid >> 5;
        float m = -3.0e38f;
#pragma unroll
        for (int i = 0; i < 16; ++i) m = fmaxf(m, sc[seg * 16 + i][lcol]);
        mxr[seg][lcol] = m;
    }
    __syncthreads();
    if (tid < 32) {
        float m = mxr[0][tid];
#pragma unroll
        for (int s = 1; s < 8; ++s) m = fmaxf(m, mxr[s][tid]);
        fin[0][tid] = m;
    }
    __syncthreads();
    {
        int lcol = tid & 31, seg = tid >> 5;
        float m = fin[0][lcol], s = 0.f;
#pragma unroll
        for (int i = 0; i < 16; ++i) s += __expf(sc[seg * 16 + i][lcol] - m);
        smr[seg][lcol] = s;
    }
    __syncthreads();
    if (tid < 32) {
        float t = 0.f;
#pragma unroll
        for (int s = 1; s < 8; ++s) t += smr[s][tid];
        fin[1][tid] = 1.0f / (t + smr[0][tid]);
    }
    __syncthreads();
    {   // write [h][l], contiguous in l
        const int lh = (tid & 1) * 16;
        float* op = ac_t + ((size_t)bn * 128 + h) * 512 + lt * 32;
#pragma unroll
        for (int j4 = 0; j4 < 4; ++j4) {
            int l0 = lh + j4 * 4;
            float4 o;
            o.x = __expf(sc[h][l0 + 0] - fin[0][l0 + 0]) * fin[1][l0 + 0];
            o.y = __expf(sc[h][l0 + 1] - fin[0][l0 + 1]) * fin[1][l0 + 1];
            o.z = __expf(sc[h][l0 + 2] - fin[0][l0 + 2]) * fin[1][l0 + 2];
            o.w = __expf(sc[h][l0 + 3] - fin[0][l0 + 3]) * fin[1][l0 + 3];
            *(float4*)(op + l0) = o;
        }
    }
}

// ---------------- fused axial attention core, MFMA bf16 ------------------------
#define ARP 136
#define VBP 136
__global__ __launch_bounds__(256) void core_mfma(const float* __restrict__ a_row,
                                                 const float* __restrict__ ac_t,
                                                 const ushort_t* __restrict__ v_t,
                                                 float* __restrict__ attn) {
    __shared__ ushort_t ar_lds[64 * ARP];          // 17.4 KB
    __shared__ ushort_t vb_lds[2][64 * VBP];       // 2 x 17.4 KB (2 h per buffer)
    const int blk = blockIdx.x;                    // lt*64 + bn: siblings share XCD
    const int lt = blk >> 6, bn = blk & 63;
    const int n = bn & 7, b = bn >> 3;
    const int tid = threadIdx.x, lane = tid & 63, wv = tid >> 6;
    const int quad = lane >> 4, lc = lane & 15;

    {   // a_row -> bf16 LDS
        const size_t abase = ((size_t)bn * L_ + lt * 64) * 128;
        int r = tid >> 2, wq = (tid & 3) * 32;
        const float* src = a_row + abase + (size_t)r * 128 + wq;
        ushort_t* dst = ar_lds + r * ARP + wq;
#pragma unroll
        for (int j = 0; j < 8; ++j) {
            float4 f = *(const float4*)(src + j * 4);
            ushort4 u;
            u.x = f2bf(f.x); u.y = f2bf(f.y); u.z = f2bf(f.z); u.w = f2bf(f.w);
            *(ushort4*)(dst + j * 4) = u;
        }
    }
    const float* act = ac_t + (size_t)bn * 65536 + lt * 64 + wv * 16 + quad * 4;
    const ushort_t* vtb = v_t + (size_t)b * 4194304 + (size_t)(n * 32) * 16384;
    const int sc_ = tid >> 3, sw = (tid & 7) * 16;
#define STAGE2(hh, bu)                                                             \
    {                                                                              \
        const ushort_t* s0 = vtb + (size_t)sc_ * 16384 + (hh) * 128 + sw;          \
        ushort_t* d0 = vb_lds[bu] + sc_ * VBP + sw;                                \
        *(uint4*)d0 = *(const uint4*)s0;                                           \
        *(uint4*)(d0 + 8) = *(const uint4*)(s0 + 8);                               \
        const ushort_t* s1 = s0 + 128;                                             \
        ushort_t* d1 = d0 + 32 * VBP;                                              \
        *(uint4*)d1 = *(const uint4*)s1;                                           \
        *(uint4*)(d1 + 8) = *(const uint4*)(s1 + 8);                               \
    }
    STAGE2(0, 0);
    __syncthreads();                    // ar + pair0 visible
    bf16x8 A[4];
#pragma unroll
    for (int kc = 0; kc < 4; ++kc)
        A[kc] = *(const bf16x8*)(ar_lds + (wv * 16 + lc) * ARP + kc * 32 + quad * 8);

    f32x4 acc0 = {0.f,0.f,0.f,0.f}, acc1 = {0.f,0.f,0.f,0.f};
    for (int hh = 0; hh < 128; hh += 2) {
        const int buf = (hh >> 1) & 1;
        if (hh) __syncthreads();        // pair(hh) visible; pair(hh-2) fully consumed
        if (hh + 2 < 128) STAGE2(hh + 2, buf ^ 1);
        float4 av0 = *(const float4*)(act + (size_t)hh * 512);
        float4 av1 = *(const float4*)(act + (size_t)(hh + 1) * 512);
        const ushort_t* vb0 = vb_lds[buf];
        const ushort_t* vb1 = vb_lds[buf] + 32 * VBP;
        f32x4 t0 = {0.f,0.f,0.f,0.f}, t1 = {0.f,0.f,0.f,0.f};
        f32x4 u0 = {0.f,0.f,0.f,0.f}, u1 = {0.f,0.f,0.f,0.f};
#pragma unroll
        for (int kc = 0; kc < 4; ++kc) {
            const int ko = kc * 32 + quad * 8;
            bf16x8 b0 = *(const bf16x8*)(vb0 + lc * VBP + ko);
            bf16x8 b1 = *(const bf16x8*)(vb0 + (16 + lc) * VBP + ko);
            bf16x8 c0 = *(const bf16x8*)(vb1 + lc * VBP + ko);
            bf16x8 c1 = *(const bf16x8*)(vb1 + (16 + lc) * VBP + ko);
            t0 = __builtin_amdgcn_mfma_f32_16x16x32_bf16(A[kc], b0, t0, 0, 0, 0);
            t1 = __builtin_amdgcn_mfma_f32_16x16x32_bf16(A[kc], b1, t1, 0, 0, 0);
            u0 = __builtin_amdgcn_mfma_f32_16x16x32_bf16(A[kc], c0, u0, 0, 0, 0);
            u1 = __builtin_amdgcn_mfma_f32_16x16x32_bf16(A[kc], c1, u1, 0, 0, 0);
        }
        acc0[0] += av0.x * t0[0] + av1.x * u0[0]; acc1[0] += av0.x * t1[0] + av1.x * u1[0];
        acc0[1] += av0.y * t0[1] + av1.y * u0[1]; acc1[1] += av0.y * t1[1] + av1.y * u1[1];
        acc0[2] += av0.z * t0[2] + av1.z * u0[2]; acc1[2] += av0.z * t1[2] + av1.z * u1[2];
        acc0[3] += av0.w * t0[3] + av1.w * u0[3]; acc1[3] += av0.w * t1[3] + av1.w * u1[3];
    }
    const int row0 = wv * 16 + quad * 4;
#pragma unroll
    for (int r = 0; r < 4; ++r) {
        size_t o = ((size_t)(lt * 64 + row0 + r) * B_ + b) * E_ + n * HD_ + lc;
        attn[o] = acc0[r];
        attn[o + 16] = acc1[r];
    }
#undef STAGE2
}

// ---------------- launch --------------------------------------------------------
extern "C" void kernel_launch(void* const* d_in, const int* in_sizes, int n_in,
                              void* d_out, int out_size, void* d_ws, size_t ws_size,
                              hipStream_t stream) {
    const float* query_row = (const float*)d_in[0];
    const float* query_col = (const float*)d_in[1];
    const float* key_row   = (const float*)d_in[2];
    const float* key_col   = (const float*)d_in[3];
    const float* value     = (const float*)d_in[4];
    const float* ipw       = (const float*)d_in[5];
    const float* ipb       = (const float*)d_in[6];
    const float* opw       = (const float*)d_in[7];
    const float* opb       = (const float*)d_in[8];
    float* out = (float*)d_out;

    char* ws = (char*)d_ws;
    float* q_row_s = (float*)ws;  ws += (size_t)4096 * 256 * 4;
    float* q_col_s = (float*)ws;  ws += (size_t)4096 * 256 * 4;
    float* krm     = (float*)ws;  ws += (size_t)262144 * 4;
    float* kcm     = (float*)ws;  ws += (size_t)262144 * 4;
    float* k_row   = (float*)ws;  ws += (size_t)262144 * 4;
    float* k_col   = (float*)ws;  ws += (size_t)262144 * 4;
    ushort_t* v_t  = (ushort_t*)ws; ws += (size_t)33554432 * 2;   // [B][256][16384]
    float* a_row   = (float*)ws;  ws += (size_t)4194304 * 4;      // [bn][l][w]
    float* ac_t    = (float*)ws;  ws += (size_t)4194304 * 4;      // [bn][h][l]
    float* attn    = (float*)ws;  ws += (size_t)4096 * 256 * 4;
    ushort_t* wbf  = (ushort_t*)ws; ws += (size_t)65536 * 2;

    const float scale = 0.17677669529663687f;   // HD^-0.5

    mean_h_kernel<<<1024, 256, 0, stream>>>(key_row, krm);
    mean_w_kernel<<<1024, 256, 0, stream>>>(key_col, kcm);
    wconv_kernel<<<64, 256, 0, stream>>>(ipw + 4 * 65536, wbf);

    gemm256<<<dim3(64, 4), 256, 0, stream>>>(query_row, ipw + 0 * 65536, ipb + 0,    q_row_s, 4096, scale);
    gemm256<<<dim3(64, 4), 256, 0, stream>>>(query_col, ipw + 1 * 65536, ipb + 256,  q_col_s, 4096, scale);
    gemm256<<<dim3(16, 4), 256, 0, stream>>>(krm,       ipw + 2 * 65536, ipb + 512,  k_row,   1024, 1.0f);
    gemm256<<<dim3(16, 4), 256, 0, stream>>>(kcm,       ipw + 3 * 65536, ipb + 768,  k_col,   1024, 1.0f);

    vproj_mfma<<<2048, 256, 0, stream>>>(value, wbf, ipb + 1024, v_t);

    scores_row<<<dim3(16, 64), 256, 0, stream>>>(q_row_s, k_row, a_row);
    scores_col<<<dim3(16, 64), 256, 0, stream>>>(q_col_s, k_col, ac_t);

    core_mfma<<<512, 256, 0, stream>>>(a_row, ac_t, v_t, attn);

    gemm256<<<dim3(64, 4), 256, 0, stream>>>(attn, opw, opb, out, 4096, 1.0f);
}